// Round 12
// baseline (290.729 us; speedup 1.0000x reference)
//
#include <hip/hip_runtime.h>

#define EPS 1e-6f
#define V_LO 0.95f
#define V_HI 1.05f

#define BIN_ELEMS 20480            // nodes per bin (fits 160 KB LDS as p+q f32)
#define MAXBINS 5
#define TPB 1024
#define CAP 4064                   // staging records per bin per block-round
#define SLOTS_B 16                 // phase-B blocks per bin (partial count)
#define EPR 4                      // edges per thread per round
#define ROUND_EDGES (TPB * EPR)    // 4096
#define MAX_SPLIT 51               // fallback path

typedef float f32x2 __attribute__((ext_vector_type(2)));
typedef unsigned long long u64;
typedef unsigned int u32;

// ---------------------------------------------------------------------------
// Kernel 0: v2[n] = nf[n,0]^2 + nf[n,1]^2
// ---------------------------------------------------------------------------
__global__ void pf_v2_kernel(const float4* __restrict__ nf4,
                             float* __restrict__ v2tab, int n_nodes) {
    int i = blockIdx.x * blockDim.x + threadIdx.x;
    if (i < n_nodes) {
        float4 f = nf4[i];
        v2tab[i] = f.x * f.x + f.y * f.y;
    }
}

// ---------------------------------------------------------------------------
// append_end: ballot-aggregated append of one record into the LDS staging
// buffer for its bin (leader lane does ONE cnt-atomic per bin per wave-step;
// per-lane same-address LDS atomics would serialize ~64x). Spill to global
// tail if staging full (statistically unreachable, kept for correctness).
// Must be called from converged code (inactive ends pass mybin = -1).
// ---------------------------------------------------------------------------
__device__ __forceinline__ void append_end(int mybin, u64 rec, int lane,
                                           int* cnt, u64* stage,
                                           int* gtail, u64* bucket, int capbin) {
    int pos = -1;
    #pragma unroll
    for (int b = 0; b < MAXBINS; ++b) {
        unsigned long long m = __ballot(mybin == b);
        if (mybin == b) {
            int rank   = (int)__popcll(m & ((1ull << lane) - 1));
            int leader = __ffsll((unsigned long long)m) - 1;
            int base = 0;
            if (lane == leader) base = atomicAdd(&cnt[b], (int)__popcll(m));
            base = __shfl(base, leader);
            pos = base + rank;
        }
    }
    if (mybin >= 0) {
        if (pos < CAP) {
            stage[mybin * CAP + pos] = rec;
        } else {                                  // rare spill, correct path
            int gp = atomicAdd(&gtail[mybin], 1);
            if (gp < capbin) bucket[(size_t)mybin * capbin + gp] = rec;
        }
    }
}

// ---------------------------------------------------------------------------
// Phase A: scan edges ONCE; per edge compute pe and ratio=(prx+e)/(pry+e);
// emit 8-B records (local_id | ratio_bf16<<16, pe_f32) into per-bin buckets
// via LDS staging + coalesced flush. qe is reconstructed as pe*ratio in
// phase B (bf16 ratio -> <=0.2% q error, threshold is 2%).
// ---------------------------------------------------------------------------
__global__ __launch_bounds__(TPB) void pf_bucket_scan(
    const float* __restrict__ v2tab,
    const int* __restrict__ ei,        // (2,E)
    const float* __restrict__ probs,
    const float* __restrict__ params,  // (E,2) flat
    u64* __restrict__ bucket,          // [nbins][capbin]
    int* __restrict__ gtail,           // [MAXBINS]
    int n_edges, int capbin, int nbins, int total_rounds)
{
    extern __shared__ u64 stage[];     // MAXBINS*CAP records
    __shared__ int cnt[MAXBINS];
    __shared__ int wbase[MAXBINS];
    int tid  = threadIdx.x;
    int lane = tid & 63;

    for (int r = blockIdx.x; r < total_rounds; r += gridDim.x) {
        if (tid < nbins) cnt[tid] = 0;
        __syncthreads();

        int ebase = r * ROUND_EDGES + tid * EPR;
        bool full = (ebase + EPR <= n_edges);
        int4 s4, d4; float4 pb4, prA, prB;
        if (full) {
            s4  = *reinterpret_cast<const int4*>(&ei[ebase]);
            d4  = *reinterpret_cast<const int4*>(&ei[n_edges + ebase]);
            pb4 = *reinterpret_cast<const float4*>(&probs[ebase]);
            prA = *reinterpret_cast<const float4*>(&params[(size_t)ebase * 2]);
            prB = *reinterpret_cast<const float4*>(&params[(size_t)ebase * 2 + 4]);
        }

        #pragma unroll
        for (int k = 0; k < EPR; ++k) {
            int e = ebase + k;
            bool v = full || (e < n_edges);
            int src, dst; float prob, prx, pry;
            if (full) {
                src  = (k == 0) ? s4.x : (k == 1) ? s4.y : (k == 2) ? s4.z : s4.w;
                dst  = (k == 0) ? d4.x : (k == 1) ? d4.y : (k == 2) ? d4.z : d4.w;
                prob = (k == 0) ? pb4.x : (k == 1) ? pb4.y : (k == 2) ? pb4.z : pb4.w;
                prx  = (k == 0) ? prA.x : (k == 1) ? prA.z : (k == 2) ? prB.x : prB.z;
                pry  = (k == 0) ? prA.y : (k == 1) ? prA.w : (k == 2) ? prB.y : prB.w;
            } else if (v) {
                src = ei[e]; dst = ei[n_edges + e]; prob = probs[e];
                prx = params[(size_t)e * 2]; pry = params[(size_t)e * 2 + 1];
            } else {
                src = 0; dst = 0; prob = 0.0f; prx = 1.0f; pry = 1.0f;
            }
            float v2 = 0.0f;
            if (v) v2 = v2tab[src];
            float pe    = v2 * prob * __builtin_amdgcn_rcpf(prx + EPS);
            float ratio = (prx + EPS) * __builtin_amdgcn_rcpf(pry + EPS);
            u32 rb = __float_as_uint(ratio);
            rb += 0x7FFFu + ((rb >> 16) & 1u);         // round-to-nearest bf16
            u32 rhi = rb >> 16;
            u32 pbits = __float_as_uint(pe);

            int bin_s = v ? (src / BIN_ELEMS) : -1;
            u32 lid_s = (u32)(src - bin_s * BIN_ELEMS);
            append_end(bin_s, ((u64)pbits << 32) | (u64)(lid_s | (rhi << 16)),
                       lane, cnt, stage, gtail, bucket, capbin);

            bool dv = v && (src != dst);
            int bin_d = dv ? (dst / BIN_ELEMS) : -1;
            u32 lid_d = dv ? (u32)(dst - bin_d * BIN_ELEMS) : 0u;
            append_end(bin_d, ((u64)pbits << 32) | (u64)(lid_d | (rhi << 16)),
                       lane, cnt, stage, gtail, bucket, capbin);
        }
        __syncthreads();

        if (tid < nbins) {
            int n = min(cnt[tid], CAP);
            wbase[tid] = atomicAdd(&gtail[tid], n);   // device atomic, 5/round
        }
        __syncthreads();

        for (int b = 0; b < nbins; ++b) {
            int n  = min(cnt[b], CAP);
            int gb = wbase[b];
            if (gb < capbin) {
                n = min(n, capbin - gb);
                u64* dstp = bucket + (size_t)b * capbin + gb;
                for (int i = tid; i < n; i += TPB)
                    __builtin_nontemporal_store(stage[b * CAP + i], &dstp[i]);
            }
        }
        __syncthreads();
    }
}

// ---------------------------------------------------------------------------
// Phase B: block (bin, slot) accumulates its dense record slice into LDS
// (SoA p/q so both ds_adds spread over all 32 banks, all 64 lanes useful),
// then writes interleaved partial[slot][bin range].
// ---------------------------------------------------------------------------
__global__ __launch_bounds__(TPB) void pf_bucket_accum(
    const u64* __restrict__ bucket,
    const int* __restrict__ gtail,
    float* __restrict__ partial,       // [SLOTS_B][n_nodes*2]
    int n_nodes, int capbin)
{
    extern __shared__ float sm[];      // p[BIN_ELEMS] + q[BIN_ELEMS]
    float* smp = sm;
    float* smq = sm + BIN_ELEMS;
    int bin  = blockIdx.x / SLOTS_B;
    int slot = blockIdx.x % SLOTS_B;
    int node_base = bin * BIN_ELEMS;

    for (int i = threadIdx.x; i < 2 * BIN_ELEMS; i += TPB) sm[i] = 0.0f;
    __syncthreads();

    int cnt   = min(gtail[bin], capbin);
    int chunk = (cnt + SLOTS_B - 1) / SLOTS_B;
    int lo = slot * chunk;
    int hi = min(lo + chunk, cnt);
    const u64* bb = bucket + (size_t)bin * capbin;
    for (int i = lo + threadIdx.x; i < hi; i += TPB) {
        u64 rec = bb[i];
        u32 w0 = (u32)rec;
        float pe    = __uint_as_float((u32)(rec >> 32));
        float ratio = __uint_as_float(w0 & 0xFFFF0000u);
        int id = (int)(w0 & 0xFFFFu);
        atomicAdd(&smp[id], pe);            // ds_add_f32, dense 64-lane
        atomicAdd(&smq[id], pe * ratio);
    }
    __syncthreads();

    int lim = min(BIN_ELEMS, n_nodes - node_base);
    float* out = partial + (size_t)slot * n_nodes * 2 + (size_t)node_base * 2;
    f32x2* out2 = reinterpret_cast<f32x2*>(out);
    for (int i = threadIdx.x; i < lim; i += TPB) {
        f32x2 vv; vv.x = smp[i]; vv.y = smq[i];
        __builtin_nontemporal_store(vv, &out2[i]);
    }
}

// ---------------------------------------------------------------------------
// FALLBACK (round-10 structure): multi-pass bin scan with predicated gather.
// Used when ws_size can't hold buckets+partials.
// ---------------------------------------------------------------------------
__global__ __launch_bounds__(TPB) void pf_edge_scan(
    const float* __restrict__ v2tab,
    const int* __restrict__ ei,
    const float* __restrict__ probs,
    const float* __restrict__ params,
    float* __restrict__ partial,       // [split][n_nodes*2]
    int n_edges, int n_nodes, int nbins, int per_chunk)
{
    extern __shared__ float lds[];
    int bin  = blockIdx.x % nbins;
    int slot = blockIdx.x / nbins;
    int node_base = bin * BIN_ELEMS;

    for (int i = threadIdx.x; i < 2 * BIN_ELEMS; i += TPB) lds[i] = 0.0f;
    __syncthreads();

    int e0 = slot * per_chunk;
    int e1 = min(e0 + per_chunk, n_edges);
    for (int e = e0 + threadIdx.x * 4; e < e1; e += TPB * 4) {
        if (e + 4 <= e1) {
            int4   s4  = *reinterpret_cast<const int4*>(&ei[e]);
            int4   d4  = *reinterpret_cast<const int4*>(&ei[n_edges + e]);
            float4 pb4 = *reinterpret_cast<const float4*>(&probs[e]);
            float4 prA = *reinterpret_cast<const float4*>(&params[(size_t)e * 2]);
            float4 prB = *reinterpret_cast<const float4*>(&params[(size_t)e * 2 + 4]);
            #pragma unroll
            for (int k = 0; k < 4; ++k) {
                int   src  = (k == 0) ? s4.x : (k == 1) ? s4.y : (k == 2) ? s4.z : s4.w;
                int   dst  = (k == 0) ? d4.x : (k == 1) ? d4.y : (k == 2) ? d4.z : d4.w;
                float prob = (k == 0) ? pb4.x : (k == 1) ? pb4.y : (k == 2) ? pb4.z : pb4.w;
                float prx  = (k == 0) ? prA.x : (k == 1) ? prA.z : (k == 2) ? prB.x : prB.z;
                float pry  = (k == 0) ? prA.y : (k == 1) ? prA.w : (k == 2) ? prB.y : prB.w;
                unsigned ls = (unsigned)(src - node_base);
                unsigned ld = (unsigned)(dst - node_base);
                bool cs = ls < (unsigned)BIN_ELEMS;
                bool cd = (ld < (unsigned)BIN_ELEMS) & (src != dst);
                if (cs | cd) {
                    float v2 = v2tab[src];
                    float pe = v2 * prob * __builtin_amdgcn_rcpf(prx + EPS);
                    float qe = v2 * prob * __builtin_amdgcn_rcpf(pry + EPS);
                    if (cs) { atomicAdd(&lds[2 * ls], pe); atomicAdd(&lds[2 * ls + 1], qe); }
                    if (cd) { atomicAdd(&lds[2 * ld], pe); atomicAdd(&lds[2 * ld + 1], qe); }
                }
            }
        } else {
            for (int t = e; t < e1; ++t) {
                int src = ei[t];
                int dst = ei[n_edges + t];
                unsigned ls = (unsigned)(src - node_base);
                unsigned ld = (unsigned)(dst - node_base);
                bool cs = ls < (unsigned)BIN_ELEMS;
                bool cd = (ld < (unsigned)BIN_ELEMS) & (src != dst);
                if (cs | cd) {
                    float v2 = v2tab[src];
                    float pe = v2 * probs[t] * __builtin_amdgcn_rcpf(params[(size_t)t * 2] + EPS);
                    float qe = v2 * probs[t] * __builtin_amdgcn_rcpf(params[(size_t)t * 2 + 1] + EPS);
                    if (cs) { atomicAdd(&lds[2 * ls], pe); atomicAdd(&lds[2 * ls + 1], qe); }
                    if (cd) { atomicAdd(&lds[2 * ld], pe); atomicAdd(&lds[2 * ld + 1], qe); }
                }
            }
        }
    }
    __syncthreads();

    int lim = min(BIN_ELEMS, n_nodes - node_base);
    float* out = partial + (size_t)slot * n_nodes * 2 + (size_t)node_base * 2;
    const f32x2* lds2 = reinterpret_cast<const f32x2*>(lds);
    f32x2* out2 = reinterpret_cast<f32x2*>(out);
    for (int i = threadIdx.x; i < lim; i += TPB)
        __builtin_nontemporal_store(lds2[i], &out2[i]);
}

// ---------------------------------------------------------------------------
// Node kernel (shared): 2 nodes/thread, sum `split` partials, loss terms,
// block-reduce, one atomic per block.
// ---------------------------------------------------------------------------
__global__ void pf_node_kernel(const float* __restrict__ nf,
                               const float* __restrict__ partial,
                               float* __restrict__ acc,
                               int n_nodes, int split) {
    int i2 = (blockIdx.x * blockDim.x + threadIdx.x) * 2;
    float c = 0.0f;
    if (i2 < n_nodes) {
        bool two = (i2 + 1) < n_nodes;
        float4 fa = *reinterpret_cast<const float4*>(&nf[(size_t)i2 * 4]);
        float4 fb = two ? *reinterpret_cast<const float4*>(&nf[(size_t)(i2 + 1) * 4])
                        : make_float4(0, 0, 0, 0);
        float pa = fa.z, qa = fa.w, pb = fb.z, qb = fb.w;
        const float* pp = partial + (size_t)i2 * 2;
        for (int s = 0; s < split; ++s) {
            float4 fl = *reinterpret_cast<const float4*>(&pp[(size_t)s * n_nodes * 2]);
            pa += fl.x; qa += fl.y;
            pb += fl.z; qb += fl.w;
        }
        float vmag = sqrtf(fa.x * fa.x + fa.y * fa.y);
        float lv = fmaxf(V_LO - vmag, 0.0f);
        float uv = fmaxf(vmag - V_HI, 0.0f);
        c = pa * pa + qa * qa + lv * lv + uv * uv;
        if (two) {
            float vmag2 = sqrtf(fb.x * fb.x + fb.y * fb.y);
            float lv2 = fmaxf(V_LO - vmag2, 0.0f);
            float uv2 = fmaxf(vmag2 - V_HI, 0.0f);
            c += pb * pb + qb * qb + lv2 * lv2 + uv2 * uv2;
        }
    }
    #pragma unroll
    for (int off = 32; off > 0; off >>= 1)
        c += __shfl_down(c, off);
    __shared__ float wsum[4];
    int lane = threadIdx.x & 63;
    int wid  = threadIdx.x >> 6;
    if (lane == 0) wsum[wid] = c;
    __syncthreads();
    if (threadIdx.x == 0) {
        float s = 0.0f;
        int nw = blockDim.x >> 6;
        for (int w = 0; w < nw; ++w) s += wsum[w];
        atomicAdd(acc, s);
    }
}

__global__ void pf_finalize_kernel(const float* __restrict__ acc,
                                   float* __restrict__ out, float inv_n) {
    out[0] = acc[0] * inv_n;
}

extern "C" void kernel_launch(void* const* d_in, const int* in_sizes, int n_in,
                              void* d_out, int out_size, void* d_ws, size_t ws_size,
                              hipStream_t stream) {
    const float* nf     = (const float*)d_in[0];
    const int*   ei     = (const int*)d_in[1];
    const float* probs  = (const float*)d_in[2];
    const float* params = (const float*)d_in[3];

    int n_nodes = in_sizes[0] / 4;
    int n_edges = in_sizes[2];
    int nbins = (n_nodes + BIN_ELEMS - 1) / BIN_ELEMS;

    // ws header: [acc f32 @0][gtail int[8] @64], zeroed each call
    float* acc   = (float*)d_ws;
    int*   gtail = (int*)((char*)d_ws + 64);
    float* v2tab = (float*)((char*)d_ws + 256);
    size_t v2_bytes = ((size_t)n_nodes * sizeof(float) + 255) & ~(size_t)255;
    char*  after_v2 = (char*)d_ws + 256 + v2_bytes;

    // bucket-path sizing
    int capbin = (int)(((long long)n_edges * 2 / nbins) * 6 / 5);   // 1.2x headroom
    size_t bucket_bytes = (size_t)nbins * capbin * sizeof(u64);
    size_t partB_bytes  = (size_t)SLOTS_B * n_nodes * 2 * sizeof(float);
    size_t need = 256 + v2_bytes + bucket_bytes + partB_bytes;
    bool use_bucket = (ws_size >= need) && (nbins <= MAXBINS);

    (void)hipMemsetAsync(d_ws, 0, 256, stream);

    pf_v2_kernel<<<(n_nodes + 255) / 256, 256, 0, stream>>>(
        (const float4*)nf, v2tab, n_nodes);

    if (use_bucket) {
        u64*   bucket  = (u64*)after_v2;
        float* partial = (float*)(after_v2 + bucket_bytes);

        size_t ldsA = (size_t)MAXBINS * CAP * sizeof(u64);          // 162,560
        size_t ldsB = (size_t)(2 * BIN_ELEMS) * sizeof(float);      // 163,840
        (void)hipFuncSetAttribute((const void*)pf_bucket_scan,
                                  hipFuncAttributeMaxDynamicSharedMemorySize, (int)ldsA);
        (void)hipFuncSetAttribute((const void*)pf_bucket_accum,
                                  hipFuncAttributeMaxDynamicSharedMemorySize, (int)ldsB);

        int total_rounds = (n_edges + ROUND_EDGES - 1) / ROUND_EDGES;
        pf_bucket_scan<<<256, TPB, ldsA, stream>>>(
            v2tab, ei, probs, params, bucket, gtail,
            n_edges, capbin, nbins, total_rounds);

        pf_bucket_accum<<<nbins * SLOTS_B, TPB, ldsB, stream>>>(
            bucket, gtail, partial, n_nodes, capbin);

        int nblocks = (n_nodes / 2 + 255) / 256;
        pf_node_kernel<<<nblocks, 256, 0, stream>>>(nf, partial, acc, n_nodes, SLOTS_B);
    } else {
        float* partial = (float*)after_v2;
        size_t slot_bytes = (size_t)n_nodes * 2 * sizeof(float);
        int split = (int)((ws_size - 256 - v2_bytes) / slot_bytes);
        if (split > MAX_SPLIT) split = MAX_SPLIT;
        if (split < 1) split = 1;
        int per_chunk = (n_edges + split - 1) / split;
        per_chunk = (per_chunk + 3) & ~3;

        size_t lds_bytes = (size_t)(2 * BIN_ELEMS) * sizeof(float);
        (void)hipFuncSetAttribute((const void*)pf_edge_scan,
                                  hipFuncAttributeMaxDynamicSharedMemorySize, (int)lds_bytes);

        pf_edge_scan<<<nbins * split, TPB, lds_bytes, stream>>>(
            v2tab, ei, probs, params, partial, n_edges, n_nodes, nbins, per_chunk);

        int nblocks = (n_nodes / 2 + 255) / 256;
        pf_node_kernel<<<nblocks, 256, 0, stream>>>(nf, partial, acc, n_nodes, split);
    }

    pf_finalize_kernel<<<1, 1, 0, stream>>>(acc, (float*)d_out,
                                            1.0f / (float)n_nodes);
}

// Round 13
// 226.462 us; speedup vs baseline: 1.2838x; 1.2838x over previous
//
#include <hip/hip_runtime.h>

#define EPS 1e-6f
#define V_LO 0.95f
#define V_HI 1.05f

#define BIN_ELEMS 20480            // nodes per bin
#define MAXBINS 5
#define TPB 1024
#define CAP 4064                   // staging records per bin per round (67 sigma)
#define SLOTS_B 24                 // phase-B blocks per bin
#define EPR 4
#define ROUND_EDGES (TPB * EPR)    // 4096
#define MAX_SPLIT 51               // fallback path

typedef float f32x2 __attribute__((ext_vector_type(2)));
typedef unsigned long long u64;
typedef unsigned int u32;

// ---------------------------------------------------------------------------
// Kernel 0: v2[n] = nf[n,0]^2 + nf[n,1]^2
// ---------------------------------------------------------------------------
__global__ void pf_v2_kernel(const float4* __restrict__ nf4,
                             float* __restrict__ v2tab, int n_nodes) {
    int i = blockIdx.x * blockDim.x + threadIdx.x;
    if (i < n_nodes) {
        float4 f = nf4[i];
        v2tab[i] = f.x * f.x + f.y * f.y;
    }
}

// Ballot-aggregated append into the per-bin LDS staging buffer. MACRO (not a
// function) so `stage`/`cnt` stay true __shared__ arrays -> ds_write/ds_add,
// not flat ops (round-12 lesson: generic-pointer LDS = flat atomics, 10x).
#define APPEND_END(MYBIN, REC) do {                                          \
    int pos_ = -1;                                                           \
    _Pragma("unroll")                                                        \
    for (int b_ = 0; b_ < MAXBINS; ++b_) {                                   \
        unsigned long long m_ = __ballot((MYBIN) == b_);                     \
        if ((MYBIN) == b_) {                                                 \
            int rank_   = (int)__popcll(m_ & ((1ull << lane) - 1));          \
            int leader_ = __ffsll((unsigned long long)m_) - 1;               \
            int base_ = 0;                                                   \
            if (lane == leader_) base_ = atomicAdd(&cnt[b_], (int)__popcll(m_)); \
            base_ = __shfl(base_, leader_);                                  \
            pos_ = base_ + rank_;                                            \
        }                                                                    \
    }                                                                        \
    if ((MYBIN) >= 0) {                                                      \
        if (pos_ < CAP) {                                                    \
            stage[(MYBIN) * CAP + pos_] = (REC);                             \
        } else {                                                             \
            int gp_ = atomicAdd(&gtail[(MYBIN)], 1);                         \
            if (gp_ < capbin) bucket[(size_t)(MYBIN) * capbin + gp_] = (REC);\
        }                                                                    \
    }                                                                        \
} while (0)

// ---------------------------------------------------------------------------
// Phase A: scan edges ONCE; per edge compute pe and ratio=(prx+e)/(pry+e);
// emit 8-B records (local_id | ratio_bf16<<16, pe_f32) into per-bin buckets
// via LDS staging + coalesced flush.
// ---------------------------------------------------------------------------
__global__ __launch_bounds__(TPB) void pf_bucket_scan(
    const float* __restrict__ v2tab,
    const int* __restrict__ ei,        // (2,E)
    const float* __restrict__ probs,
    const float* __restrict__ params,  // (E,2) flat
    u64* __restrict__ bucket,          // [nbins][capbin]
    int* __restrict__ gtail,           // [MAXBINS]
    int n_edges, int capbin, int nbins, int total_rounds)
{
    extern __shared__ u64 stage[];     // MAXBINS*CAP records
    __shared__ int cnt[MAXBINS];
    __shared__ int wbase[MAXBINS];
    int tid  = threadIdx.x;
    int lane = tid & 63;

    for (int r = blockIdx.x; r < total_rounds; r += gridDim.x) {
        if (tid < nbins) cnt[tid] = 0;
        __syncthreads();

        int ebase = r * ROUND_EDGES + tid * EPR;
        bool full = (ebase + EPR <= n_edges);
        int4 s4, d4; float4 pb4, prA, prB;
        if (full) {
            s4  = *reinterpret_cast<const int4*>(&ei[ebase]);
            d4  = *reinterpret_cast<const int4*>(&ei[n_edges + ebase]);
            pb4 = *reinterpret_cast<const float4*>(&probs[ebase]);
            prA = *reinterpret_cast<const float4*>(&params[(size_t)ebase * 2]);
            prB = *reinterpret_cast<const float4*>(&params[(size_t)ebase * 2 + 4]);
        }

        #pragma unroll
        for (int k = 0; k < EPR; ++k) {
            int e = ebase + k;
            bool v = full || (e < n_edges);
            int src, dst; float prob, prx, pry;
            if (full) {
                src  = (k == 0) ? s4.x : (k == 1) ? s4.y : (k == 2) ? s4.z : s4.w;
                dst  = (k == 0) ? d4.x : (k == 1) ? d4.y : (k == 2) ? d4.z : d4.w;
                prob = (k == 0) ? pb4.x : (k == 1) ? pb4.y : (k == 2) ? pb4.z : pb4.w;
                prx  = (k == 0) ? prA.x : (k == 1) ? prA.z : (k == 2) ? prB.x : prB.z;
                pry  = (k == 0) ? prA.y : (k == 1) ? prA.w : (k == 2) ? prB.y : prB.w;
            } else if (v) {
                src = ei[e]; dst = ei[n_edges + e]; prob = probs[e];
                prx = params[(size_t)e * 2]; pry = params[(size_t)e * 2 + 1];
            } else {
                src = 0; dst = 0; prob = 0.0f; prx = 1.0f; pry = 1.0f;
            }
            float v2 = 0.0f;
            if (v) v2 = v2tab[src];
            float pe    = v2 * prob * __builtin_amdgcn_rcpf(prx + EPS);
            float ratio = (prx + EPS) * __builtin_amdgcn_rcpf(pry + EPS);
            u32 rb = __float_as_uint(ratio);
            rb += 0x7FFFu + ((rb >> 16) & 1u);         // round-to-nearest bf16
            u32 rhi = rb >> 16;
            u32 pbits = __float_as_uint(pe);

            int bin_s = v ? (src / BIN_ELEMS) : -1;
            u32 lid_s = (u32)(src - bin_s * BIN_ELEMS);
            u64 rec_s = ((u64)pbits << 32) | (u64)(lid_s | (rhi << 16));
            APPEND_END(bin_s, rec_s);

            bool dv = v && (src != dst);
            int bin_d = dv ? (dst / BIN_ELEMS) : -1;
            u32 lid_d = dv ? (u32)(dst - bin_d * BIN_ELEMS) : 0u;
            u64 rec_d = ((u64)pbits << 32) | (u64)(lid_d | (rhi << 16));
            APPEND_END(bin_d, rec_d);
        }
        __syncthreads();

        if (tid < nbins) {
            int n = min(cnt[tid], CAP);
            wbase[tid] = atomicAdd(&gtail[tid], n);
        }
        __syncthreads();

        for (int b = 0; b < nbins; ++b) {
            int n  = min(cnt[b], CAP);
            int gb = wbase[b];
            if (gb < capbin) {
                n = min(n, capbin - gb);
                u64* dstp = bucket + (size_t)b * capbin + gb;
                for (int i = tid; i < n; i += TPB)
                    __builtin_nontemporal_store(stage[b * CAP + i], &dstp[i]);
            }
        }
        __syncthreads();
    }
}

// ---------------------------------------------------------------------------
// Phase B: block (bin, slot) accumulates its dense record slice into LDS
// via DIRECT sm[] indexing (ds_add_f32), then writes partial[slot] bin slice.
// ---------------------------------------------------------------------------
__global__ __launch_bounds__(TPB) void pf_bucket_accum(
    const u64* __restrict__ bucket,
    const int* __restrict__ gtail,
    float* __restrict__ partial,       // [SLOTS_B][n_nodes*2]
    int n_nodes, int capbin)
{
    extern __shared__ float sm[];      // p[BIN_ELEMS] then q[BIN_ELEMS]
    int bin  = blockIdx.x / SLOTS_B;
    int slot = blockIdx.x % SLOTS_B;
    int node_base = bin * BIN_ELEMS;
    int tid = threadIdx.x;

    for (int i = tid; i < 2 * BIN_ELEMS; i += TPB) sm[i] = 0.0f;
    __syncthreads();

    int cnt   = min(gtail[bin], capbin);
    int chunk = (cnt + SLOTS_B - 1) / SLOTS_B;
    int lo = slot * chunk;
    int hi = min(lo + chunk, cnt);
    const u64* bb = bucket + (size_t)bin * capbin;

    int i = lo + tid;
    for (; i + TPB < hi; i += 2 * TPB) {          // 2x unroll, indep loads
        u64 r0 = bb[i];
        u64 r1 = bb[i + TPB];
        u32 w0 = (u32)r0, w1 = (u32)r1;
        float pe0 = __uint_as_float((u32)(r0 >> 32));
        float pe1 = __uint_as_float((u32)(r1 >> 32));
        float ra0 = __uint_as_float(w0 & 0xFFFF0000u);
        float ra1 = __uint_as_float(w1 & 0xFFFF0000u);
        int id0 = (int)(w0 & 0xFFFFu);
        int id1 = (int)(w1 & 0xFFFFu);
        atomicAdd(&sm[id0], pe0);
        atomicAdd(&sm[BIN_ELEMS + id0], pe0 * ra0);
        atomicAdd(&sm[id1], pe1);
        atomicAdd(&sm[BIN_ELEMS + id1], pe1 * ra1);
    }
    for (; i < hi; i += TPB) {
        u64 r0 = bb[i];
        u32 w0 = (u32)r0;
        float pe0 = __uint_as_float((u32)(r0 >> 32));
        float ra0 = __uint_as_float(w0 & 0xFFFF0000u);
        int id0 = (int)(w0 & 0xFFFFu);
        atomicAdd(&sm[id0], pe0);
        atomicAdd(&sm[BIN_ELEMS + id0], pe0 * ra0);
    }
    __syncthreads();

    int lim = min(BIN_ELEMS, n_nodes - node_base);
    float* out = partial + (size_t)slot * n_nodes * 2 + (size_t)node_base * 2;
    for (int i2 = tid; i2 < lim; i2 += TPB) {
        f32x2 vv; vv.x = sm[i2]; vv.y = sm[BIN_ELEMS + i2];
        __builtin_nontemporal_store(vv, &reinterpret_cast<f32x2*>(out)[i2]);
    }
}

// ---------------------------------------------------------------------------
// FALLBACK (round-10 champion): 5-pass bin scan with predicated gather.
// ---------------------------------------------------------------------------
__global__ __launch_bounds__(TPB) void pf_edge_scan(
    const float* __restrict__ v2tab,
    const int* __restrict__ ei,
    const float* __restrict__ probs,
    const float* __restrict__ params,
    float* __restrict__ partial,       // [split][n_nodes*2]
    int n_edges, int n_nodes, int nbins, int per_chunk)
{
    extern __shared__ float lds[];
    int bin  = blockIdx.x % nbins;
    int slot = blockIdx.x / nbins;
    int node_base = bin * BIN_ELEMS;

    for (int i = threadIdx.x; i < 2 * BIN_ELEMS; i += TPB) lds[i] = 0.0f;
    __syncthreads();

    int e0 = slot * per_chunk;
    int e1 = min(e0 + per_chunk, n_edges);
    for (int e = e0 + threadIdx.x * 4; e < e1; e += TPB * 4) {
        if (e + 4 <= e1) {
            int4   s4  = *reinterpret_cast<const int4*>(&ei[e]);
            int4   d4  = *reinterpret_cast<const int4*>(&ei[n_edges + e]);
            float4 pb4 = *reinterpret_cast<const float4*>(&probs[e]);
            float4 prA = *reinterpret_cast<const float4*>(&params[(size_t)e * 2]);
            float4 prB = *reinterpret_cast<const float4*>(&params[(size_t)e * 2 + 4]);
            #pragma unroll
            for (int k = 0; k < 4; ++k) {
                int   src  = (k == 0) ? s4.x : (k == 1) ? s4.y : (k == 2) ? s4.z : s4.w;
                int   dst  = (k == 0) ? d4.x : (k == 1) ? d4.y : (k == 2) ? d4.z : d4.w;
                float prob = (k == 0) ? pb4.x : (k == 1) ? pb4.y : (k == 2) ? pb4.z : pb4.w;
                float prx  = (k == 0) ? prA.x : (k == 1) ? prA.z : (k == 2) ? prB.x : prB.z;
                float pry  = (k == 0) ? prA.y : (k == 1) ? prA.w : (k == 2) ? prB.y : prB.w;
                unsigned ls = (unsigned)(src - node_base);
                unsigned ld = (unsigned)(dst - node_base);
                bool cs = ls < (unsigned)BIN_ELEMS;
                bool cd = (ld < (unsigned)BIN_ELEMS) & (src != dst);
                if (cs | cd) {
                    float v2 = v2tab[src];
                    float pe = v2 * prob * __builtin_amdgcn_rcpf(prx + EPS);
                    float qe = v2 * prob * __builtin_amdgcn_rcpf(pry + EPS);
                    if (cs) { atomicAdd(&lds[2 * ls], pe); atomicAdd(&lds[2 * ls + 1], qe); }
                    if (cd) { atomicAdd(&lds[2 * ld], pe); atomicAdd(&lds[2 * ld + 1], qe); }
                }
            }
        } else {
            for (int t = e; t < e1; ++t) {
                int src = ei[t];
                int dst = ei[n_edges + t];
                unsigned ls = (unsigned)(src - node_base);
                unsigned ld = (unsigned)(dst - node_base);
                bool cs = ls < (unsigned)BIN_ELEMS;
                bool cd = (ld < (unsigned)BIN_ELEMS) & (src != dst);
                if (cs | cd) {
                    float v2 = v2tab[src];
                    float pe = v2 * probs[t] * __builtin_amdgcn_rcpf(params[(size_t)t * 2] + EPS);
                    float qe = v2 * probs[t] * __builtin_amdgcn_rcpf(params[(size_t)t * 2 + 1] + EPS);
                    if (cs) { atomicAdd(&lds[2 * ls], pe); atomicAdd(&lds[2 * ls + 1], qe); }
                    if (cd) { atomicAdd(&lds[2 * ld], pe); atomicAdd(&lds[2 * ld + 1], qe); }
                }
            }
        }
    }
    __syncthreads();

    int lim = min(BIN_ELEMS, n_nodes - node_base);
    float* out = partial + (size_t)slot * n_nodes * 2 + (size_t)node_base * 2;
    for (int i = threadIdx.x; i < lim; i += TPB) {
        f32x2 vv; vv.x = lds[2 * i]; vv.y = lds[2 * i + 1];
        __builtin_nontemporal_store(vv, &reinterpret_cast<f32x2*>(out)[i]);
    }
}

// ---------------------------------------------------------------------------
// Node kernel: 2 nodes/thread, sum `split` partials, loss, block-reduce.
// ---------------------------------------------------------------------------
__global__ void pf_node_kernel(const float* __restrict__ nf,
                               const float* __restrict__ partial,
                               float* __restrict__ acc,
                               int n_nodes, int split) {
    int i2 = (blockIdx.x * blockDim.x + threadIdx.x) * 2;
    float c = 0.0f;
    if (i2 < n_nodes) {
        bool two = (i2 + 1) < n_nodes;
        float4 fa = *reinterpret_cast<const float4*>(&nf[(size_t)i2 * 4]);
        float4 fb = two ? *reinterpret_cast<const float4*>(&nf[(size_t)(i2 + 1) * 4])
                        : make_float4(0, 0, 0, 0);
        float pa = fa.z, qa = fa.w, pb = fb.z, qb = fb.w;
        const float* pp = partial + (size_t)i2 * 2;
        for (int s = 0; s < split; ++s) {
            float4 fl = *reinterpret_cast<const float4*>(&pp[(size_t)s * n_nodes * 2]);
            pa += fl.x; qa += fl.y;
            pb += fl.z; qb += fl.w;
        }
        float vmag = sqrtf(fa.x * fa.x + fa.y * fa.y);
        float lv = fmaxf(V_LO - vmag, 0.0f);
        float uv = fmaxf(vmag - V_HI, 0.0f);
        c = pa * pa + qa * qa + lv * lv + uv * uv;
        if (two) {
            float vmag2 = sqrtf(fb.x * fb.x + fb.y * fb.y);
            float lv2 = fmaxf(V_LO - vmag2, 0.0f);
            float uv2 = fmaxf(vmag2 - V_HI, 0.0f);
            c += pb * pb + qb * qb + lv2 * lv2 + uv2 * uv2;
        }
    }
    #pragma unroll
    for (int off = 32; off > 0; off >>= 1)
        c += __shfl_down(c, off);
    __shared__ float wsum[4];
    int lane = threadIdx.x & 63;
    int wid  = threadIdx.x >> 6;
    if (lane == 0) wsum[wid] = c;
    __syncthreads();
    if (threadIdx.x == 0) {
        float s = 0.0f;
        int nw = blockDim.x >> 6;
        for (int w = 0; w < nw; ++w) s += wsum[w];
        atomicAdd(acc, s);
    }
}

__global__ void pf_finalize_kernel(const float* __restrict__ acc,
                                   float* __restrict__ out, float inv_n) {
    out[0] = acc[0] * inv_n;
}

extern "C" void kernel_launch(void* const* d_in, const int* in_sizes, int n_in,
                              void* d_out, int out_size, void* d_ws, size_t ws_size,
                              hipStream_t stream) {
    const float* nf     = (const float*)d_in[0];
    const int*   ei     = (const int*)d_in[1];
    const float* probs  = (const float*)d_in[2];
    const float* params = (const float*)d_in[3];

    int n_nodes = in_sizes[0] / 4;
    int n_edges = in_sizes[2];
    int nbins = (n_nodes + BIN_ELEMS - 1) / BIN_ELEMS;

    float* acc   = (float*)d_ws;
    int*   gtail = (int*)((char*)d_ws + 64);
    float* v2tab = (float*)((char*)d_ws + 256);
    size_t v2_bytes = ((size_t)n_nodes * sizeof(float) + 255) & ~(size_t)255;
    char*  after_v2 = (char*)d_ws + 256 + v2_bytes;

    // bucket-path sizing: 1.05x headroom (63 sigma) + correct spill path
    int capbin = (int)(((long long)n_edges * 2 / nbins) * 21 / 20);
    size_t bucket_bytes = (size_t)nbins * capbin * sizeof(u64);
    size_t partB_bytes  = (size_t)SLOTS_B * n_nodes * 2 * sizeof(float);
    size_t need = 256 + v2_bytes + bucket_bytes + partB_bytes;
    bool use_bucket = (ws_size >= need) && (nbins <= MAXBINS);

    (void)hipMemsetAsync(d_ws, 0, 256, stream);

    pf_v2_kernel<<<(n_nodes + 255) / 256, 256, 0, stream>>>(
        (const float4*)nf, v2tab, n_nodes);

    if (use_bucket) {
        u64*   bucket  = (u64*)after_v2;
        float* partial = (float*)(after_v2 + bucket_bytes);

        size_t ldsA = (size_t)MAXBINS * CAP * sizeof(u64);          // 162,560
        size_t ldsB = (size_t)(2 * BIN_ELEMS) * sizeof(float);      // 163,840
        (void)hipFuncSetAttribute((const void*)pf_bucket_scan,
                                  hipFuncAttributeMaxDynamicSharedMemorySize, (int)ldsA);
        (void)hipFuncSetAttribute((const void*)pf_bucket_accum,
                                  hipFuncAttributeMaxDynamicSharedMemorySize, (int)ldsB);

        int total_rounds = (n_edges + ROUND_EDGES - 1) / ROUND_EDGES;
        pf_bucket_scan<<<256, TPB, ldsA, stream>>>(
            v2tab, ei, probs, params, bucket, gtail,
            n_edges, capbin, nbins, total_rounds);

        pf_bucket_accum<<<nbins * SLOTS_B, TPB, ldsB, stream>>>(
            bucket, gtail, partial, n_nodes, capbin);

        int nblocks = (n_nodes / 2 + 255) / 256;
        pf_node_kernel<<<nblocks, 256, 0, stream>>>(nf, partial, acc, n_nodes, SLOTS_B);
    } else {
        float* partial = (float*)after_v2;
        size_t slot_bytes = (size_t)n_nodes * 2 * sizeof(float);
        int split = (int)((ws_size - 256 - v2_bytes) / slot_bytes);
        if (split > MAX_SPLIT) split = MAX_SPLIT;
        if (split < 1) split = 1;
        int per_chunk = (n_edges + split - 1) / split;
        per_chunk = (per_chunk + 3) & ~3;

        size_t lds_bytes = (size_t)(2 * BIN_ELEMS) * sizeof(float);
        (void)hipFuncSetAttribute((const void*)pf_edge_scan,
                                  hipFuncAttributeMaxDynamicSharedMemorySize, (int)lds_bytes);

        pf_edge_scan<<<nbins * split, TPB, lds_bytes, stream>>>(
            v2tab, ei, probs, params, partial, n_edges, n_nodes, nbins, per_chunk);

        int nblocks = (n_nodes / 2 + 255) / 256;
        pf_node_kernel<<<nblocks, 256, 0, stream>>>(nf, partial, acc, n_nodes, split);
    }

    pf_finalize_kernel<<<1, 1, 0, stream>>>(acc, (float*)d_out,
                                            1.0f / (float)n_nodes);
}

// Round 14
// 132.399 us; speedup vs baseline: 2.1959x; 1.7104x over previous
//
#include <hip/hip_runtime.h>

#define EPS 1e-6f
#define V_LO 0.95f
#define V_HI 1.05f

#define BIN_ELEMS 20480            // 2 floats/node * 20480 = 160 KB LDS
#define TPB 1024                   // 16 waves, 1 block/CU
#define MAX_SPLIT 51               // 5 bins * 51 slots = 255 blocks ~ 1/CU
#define BATCH 4

typedef float f32x2 __attribute__((ext_vector_type(2)));
typedef unsigned int u32;

// ---------------------------------------------------------------------------
// Kernel 0: v2[n] = nf[n,0]^2 + nf[n,1]^2  (400 KB table)
// ---------------------------------------------------------------------------
__global__ void pf_v2_kernel(const float4* __restrict__ nf4,
                             float* __restrict__ v2tab, int n_nodes) {
    int i = blockIdx.x * blockDim.x + threadIdx.x;
    if (i < n_nodes) {
        float4 f = nf4[i];
        v2tab[i] = f.x * f.x + f.y * f.y;
    }
}

__device__ __forceinline__ u32 bf16_hi(float x) {   // round-to-nearest bf16, return high-16 in low bits
    u32 b = __float_as_uint(x);
    b += 0x7FFFu + ((b >> 16) & 1u);
    return b >> 16;
}

// ---------------------------------------------------------------------------
// Kernel 0.5: one pass over edges; pe,qe computed ONCE, packed bf16x2 into
// u32 pq[e]. Scan passes then never touch probs/params/v2tab again:
// 5-pass stream bytes drop 320 MB -> 192 MB.
// unpack: pe = asfloat(w<<16), qe = asfloat(w & 0xFFFF0000).
// ---------------------------------------------------------------------------
__global__ __launch_bounds__(256) void pf_pq_kernel(
    const float* __restrict__ v2tab,
    const int* __restrict__ ei,        // src half used
    const float* __restrict__ probs,
    const float* __restrict__ params,  // (E,2) flat
    u32* __restrict__ pq, int n_edges)
{
    int e = (blockIdx.x * blockDim.x + threadIdx.x) * BATCH;
    if (e >= n_edges) return;
    if (e + BATCH <= n_edges) {
        int4   s4  = *reinterpret_cast<const int4*>(&ei[e]);
        float4 pb4 = *reinterpret_cast<const float4*>(&probs[e]);
        float4 prA = *reinterpret_cast<const float4*>(&params[(size_t)e * 2]);
        float4 prB = *reinterpret_cast<const float4*>(&params[(size_t)e * 2 + 4]);
        float v2_0 = v2tab[s4.x];
        float v2_1 = v2tab[s4.y];
        float v2_2 = v2tab[s4.z];
        float v2_3 = v2tab[s4.w];
        uint4 out;
        {
            float pe = v2_0 * pb4.x * __builtin_amdgcn_rcpf(prA.x + EPS);
            float qe = v2_0 * pb4.x * __builtin_amdgcn_rcpf(prA.y + EPS);
            out.x = bf16_hi(pe) | (bf16_hi(qe) << 16);
        }
        {
            float pe = v2_1 * pb4.y * __builtin_amdgcn_rcpf(prA.z + EPS);
            float qe = v2_1 * pb4.y * __builtin_amdgcn_rcpf(prA.w + EPS);
            out.y = bf16_hi(pe) | (bf16_hi(qe) << 16);
        }
        {
            float pe = v2_2 * pb4.z * __builtin_amdgcn_rcpf(prB.x + EPS);
            float qe = v2_2 * pb4.z * __builtin_amdgcn_rcpf(prB.y + EPS);
            out.z = bf16_hi(pe) | (bf16_hi(qe) << 16);
        }
        {
            float pe = v2_3 * pb4.w * __builtin_amdgcn_rcpf(prB.z + EPS);
            float qe = v2_3 * pb4.w * __builtin_amdgcn_rcpf(prB.w + EPS);
            out.w = bf16_hi(pe) | (bf16_hi(qe) << 16);
        }
        *reinterpret_cast<uint4*>(&pq[e]) = out;
    } else {
        for (int t = e; t < n_edges; ++t) {
            float v2 = v2tab[ei[t]];
            float pe = v2 * probs[t] * __builtin_amdgcn_rcpf(params[(size_t)t * 2] + EPS);
            float qe = v2 * probs[t] * __builtin_amdgcn_rcpf(params[(size_t)t * 2 + 1] + EPS);
            pq[t] = bf16_hi(pe) | (bf16_hi(qe) << 16);
        }
    }
}

// ---------------------------------------------------------------------------
// Kernel 1: edge scan. Block (slot, bin) scans chunk `slot`: 3 stream loads
// per 4 edges (src, dst, pq) — no gather, no divide. Unpack + ds_add_f32
// only for ends in this bin. Nontemporal writeback of bin slice.
// LDS: node i -> lds[2*i] (p), lds[2*i+1] (q).
// ---------------------------------------------------------------------------
__global__ __launch_bounds__(TPB) void pf_edge_scan(
    const int* __restrict__ ei,        // (2,E): [0..E)=src, [E..2E)=dst
    const u32* __restrict__ pq,        // packed bf16 pe|qe
    float* __restrict__ partial,       // [split][n_nodes*2]
    int n_edges, int n_nodes, int nbins, int per_chunk)
{
    extern __shared__ float lds[];     // 2*BIN_ELEMS floats
    int bin  = blockIdx.x % nbins;
    int slot = blockIdx.x / nbins;
    int node_base = bin * BIN_ELEMS;

    for (int i = threadIdx.x; i < 2 * BIN_ELEMS; i += TPB)
        lds[i] = 0.0f;
    __syncthreads();

    int e0 = slot * per_chunk;                    // per_chunk % 4 == 0
    int e1 = min(e0 + per_chunk, n_edges);

    for (int e = e0 + threadIdx.x * BATCH; e < e1; e += TPB * BATCH) {
        if (e + BATCH <= e1) {
            int4  s4 = *reinterpret_cast<const int4*>(&ei[e]);
            int4  d4 = *reinterpret_cast<const int4*>(&ei[n_edges + e]);
            uint4 w4 = *reinterpret_cast<const uint4*>(&pq[e]);

            #pragma unroll
            for (int k = 0; k < BATCH; ++k) {
                int src = (k == 0) ? s4.x : (k == 1) ? s4.y : (k == 2) ? s4.z : s4.w;
                int dst = (k == 0) ? d4.x : (k == 1) ? d4.y : (k == 2) ? d4.z : d4.w;
                u32 w   = (k == 0) ? w4.x : (k == 1) ? w4.y : (k == 2) ? w4.z : w4.w;

                unsigned ls = (unsigned)(src - node_base);
                unsigned ld = (unsigned)(dst - node_base);
                bool cs = ls < (unsigned)BIN_ELEMS;
                bool cd = (ld < (unsigned)BIN_ELEMS) & (src != dst);
                if (cs | cd) {
                    float pe = __uint_as_float(w << 16);
                    float qe = __uint_as_float(w & 0xFFFF0000u);
                    if (cs) {
                        atomicAdd(&lds[2 * ls],     pe);   // ds_add_f32
                        atomicAdd(&lds[2 * ls + 1], qe);
                    }
                    if (cd) {
                        atomicAdd(&lds[2 * ld],     pe);
                        atomicAdd(&lds[2 * ld + 1], qe);
                    }
                }
            }
        } else {
            for (int t = e; t < e1; ++t) {          // cold tail, scalar
                int src = ei[t];
                int dst = ei[n_edges + t];
                u32 w   = pq[t];
                unsigned ls = (unsigned)(src - node_base);
                unsigned ld = (unsigned)(dst - node_base);
                bool cs = ls < (unsigned)BIN_ELEMS;
                bool cd = (ld < (unsigned)BIN_ELEMS) & (src != dst);
                if (cs | cd) {
                    float pe = __uint_as_float(w << 16);
                    float qe = __uint_as_float(w & 0xFFFF0000u);
                    if (cs) { atomicAdd(&lds[2 * ls], pe); atomicAdd(&lds[2 * ls + 1], qe); }
                    if (cd) { atomicAdd(&lds[2 * ld], pe); atomicAdd(&lds[2 * ld + 1], qe); }
                }
            }
        }
    }
    __syncthreads();

    int lim = min(BIN_ELEMS, n_nodes - node_base);
    float* out = partial + (size_t)slot * n_nodes * 2 + (size_t)node_base * 2;
    for (int i = threadIdx.x; i < lim; i += TPB) {
        f32x2 vv; vv.x = lds[2 * i]; vv.y = lds[2 * i + 1];
        __builtin_nontemporal_store(vv, &reinterpret_cast<f32x2*>(out)[i]);
    }
}

// ---------------------------------------------------------------------------
// Kernel 2: 2 nodes/thread, sum `split` partials, loss, block-reduce,
// one atomic per block.
// ---------------------------------------------------------------------------
__global__ void pf_node_kernel(const float* __restrict__ nf,
                               const float* __restrict__ partial,
                               float* __restrict__ acc,
                               int n_nodes, int split) {
    int i2 = (blockIdx.x * blockDim.x + threadIdx.x) * 2;
    float c = 0.0f;
    if (i2 < n_nodes) {
        bool two = (i2 + 1) < n_nodes;
        float4 fa = *reinterpret_cast<const float4*>(&nf[(size_t)i2 * 4]);
        float4 fb = two ? *reinterpret_cast<const float4*>(&nf[(size_t)(i2 + 1) * 4])
                        : make_float4(0, 0, 0, 0);
        float pa = fa.z, qa = fa.w, pb = fb.z, qb = fb.w;
        const float* pp = partial + (size_t)i2 * 2;
        for (int s = 0; s < split; ++s) {
            float4 fl = *reinterpret_cast<const float4*>(&pp[(size_t)s * n_nodes * 2]);
            pa += fl.x; qa += fl.y;
            pb += fl.z; qb += fl.w;
        }
        float vmag = sqrtf(fa.x * fa.x + fa.y * fa.y);
        float lv = fmaxf(V_LO - vmag, 0.0f);
        float uv = fmaxf(vmag - V_HI, 0.0f);
        c = pa * pa + qa * qa + lv * lv + uv * uv;
        if (two) {
            float vmag2 = sqrtf(fb.x * fb.x + fb.y * fb.y);
            float lv2 = fmaxf(V_LO - vmag2, 0.0f);
            float uv2 = fmaxf(vmag2 - V_HI, 0.0f);
            c += pb * pb + qb * qb + lv2 * lv2 + uv2 * uv2;
        }
    }
    #pragma unroll
    for (int off = 32; off > 0; off >>= 1)
        c += __shfl_down(c, off);
    __shared__ float wsum[4];
    int lane = threadIdx.x & 63;
    int wid  = threadIdx.x >> 6;
    if (lane == 0) wsum[wid] = c;
    __syncthreads();
    if (threadIdx.x == 0) {
        float s = 0.0f;
        int nw = blockDim.x >> 6;
        for (int w = 0; w < nw; ++w) s += wsum[w];
        atomicAdd(acc, s);
    }
}

__global__ void pf_finalize_kernel(const float* __restrict__ acc,
                                   float* __restrict__ out, float inv_n) {
    out[0] = acc[0] * inv_n;
}

extern "C" void kernel_launch(void* const* d_in, const int* in_sizes, int n_in,
                              void* d_out, int out_size, void* d_ws, size_t ws_size,
                              hipStream_t stream) {
    const float* nf     = (const float*)d_in[0];    // (N,4) f32
    const int*   ei     = (const int*)d_in[1];      // (2,E) int
    const float* probs  = (const float*)d_in[2];    // (E,) f32
    const float* params = (const float*)d_in[3];    // (E,2) f32 flat

    int n_nodes = in_sizes[0] / 4;
    int n_edges = in_sizes[2];

    // ws layout: [acc pad 256][v2: N f32 pad 256][pq: E u32 pad 256][partial]
    float* acc   = (float*)d_ws;
    float* v2tab = (float*)((char*)d_ws + 256);
    size_t v2_bytes = ((size_t)n_nodes * sizeof(float) + 255) & ~(size_t)255;
    u32*   pq    = (u32*)((char*)d_ws + 256 + v2_bytes);
    size_t pq_bytes = ((size_t)n_edges * sizeof(u32) + 255) & ~(size_t)255;
    float* partial = (float*)((char*)d_ws + 256 + v2_bytes + pq_bytes);

    size_t slot_bytes = (size_t)n_nodes * 2 * sizeof(float);
    long long avail = (long long)ws_size - 256 - (long long)v2_bytes - (long long)pq_bytes;
    int split = (avail > 0) ? (int)(avail / (long long)slot_bytes) : 0;
    if (split > MAX_SPLIT) split = MAX_SPLIT;
    if (split < 1) split = 1;   // ws proven >= ~73 MB (r12/13 bucket path ran); need ~54 MB

    int nbins = (n_nodes + BIN_ELEMS - 1) / BIN_ELEMS;
    int per_chunk = (n_edges + split - 1) / split;
    per_chunk = (per_chunk + 3) & ~3;               // multiple of BATCH

    size_t lds_bytes = (size_t)(2 * BIN_ELEMS) * sizeof(float);   // 160 KB
    (void)hipFuncSetAttribute((const void*)pf_edge_scan,
                              hipFuncAttributeMaxDynamicSharedMemorySize,
                              (int)lds_bytes);

    (void)hipMemsetAsync(d_ws, 0, 256, stream);     // acc only

    pf_v2_kernel<<<(n_nodes + 255) / 256, 256, 0, stream>>>(
        (const float4*)nf, v2tab, n_nodes);

    int pq_blocks = (n_edges + 256 * BATCH - 1) / (256 * BATCH);
    pf_pq_kernel<<<pq_blocks, 256, 0, stream>>>(
        v2tab, ei, probs, params, pq, n_edges);

    pf_edge_scan<<<nbins * split, TPB, lds_bytes, stream>>>(
        ei, pq, partial, n_edges, n_nodes, nbins, per_chunk);

    int nblocks = (n_nodes / 2 + 255) / 256;
    pf_node_kernel<<<nblocks, 256, 0, stream>>>(nf, partial, acc, n_nodes, split);

    pf_finalize_kernel<<<1, 1, 0, stream>>>(acc, (float*)d_out,
                                            1.0f / (float)n_nodes);
}